// Round 9
// baseline (90.925 us; speedup 1.0000x reference)
//
#include <hip/hip_runtime.h>
#include <hip/hip_bf16.h>
#include <math.h>

#define EMBED  128
#define NUM_C  64
#define EPS    1e-5f
#define NPB    32            // nodes per block (one tile per block)
#define LDSROW 132           // floats; padded rows, bank-balanced b128 pattern
#define BANKS  16            // shadow accumulator banks (kill atomic line contention)
#define BSTRIDE 80           // floats per bank: 64 col-sums + 1 mask + pad

typedef __attribute__((ext_vector_type(8))) short bf16x8;   // MFMA A/B frag
typedef __attribute__((ext_vector_type(4))) float f32x4;    // MFMA C/D frag

__device__ __forceinline__ bf16x8 pack8(float4 x, float4 y) {
    __hip_bfloat162 p0 = __float22bfloat162_rn(float2{x.x, x.y});
    __hip_bfloat162 p1 = __float22bfloat162_rn(float2{x.z, x.w});
    __hip_bfloat162 p2 = __float22bfloat162_rn(float2{y.x, y.y});
    __hip_bfloat162 p3 = __float22bfloat162_rn(float2{y.z, y.w});
    union { __hip_bfloat162 h[4]; bf16x8 v; } u;
    u.h[0] = p0; u.h[1] = p1; u.h[2] = p2; u.h[3] = p3;
    return u.v;
}

// Single compute kernel. One block = one 32x64 tile: A staged to LDS once,
// B packed to bf16 frags once/wave. Graph-mean finalized IN-KERNEL by the
// last block (atomic banks + counter + device fences -- hipCUB-style
// single-pass reduce; valid across XCDs).
// R7 post-mortem: cooperative grid.sync cost ~60us here -- never again.
// R8 post-mortem: every extra graph node costs duration + transition gap.
__global__ __launch_bounds__(256) void cd_main(
    const float* __restrict__ node_repr,   // [N,128]
    const float* __restrict__ mask,        // [N,1]
    const float* __restrict__ cent,        // [64,128]
    float* __restrict__ out,               // [64 + N*64]
    float* __restrict__ acc,               // [BANKS*BSTRIDE] zeroed banks
    unsigned* __restrict__ cnt,            // zeroed block counter
    int N, int nb)
{
    __shared__ float sa[NPB * LDSROW];     // 16896 B A tile (padded rows)
    __shared__ float s_su[NPB];            // per-row ||u||^2
    __shared__ float s_ms[NPB];            // per-row mask (0 for OOB rows)
    __shared__ unsigned s_last;

    const int tid  = threadIdx.x;
    const int lane = tid & 63;
    const int wv   = tid >> 6;
    const int quad = lane >> 4;            // 0..3 (k-slice)
    const int lm   = lane & 15;            // A row in tile / B col / D col
    const int cw   = wv * 16;              // wave's centroid group base
    const int node0 = blockIdx.x * NPB;

    // ---- A staging: thread owns row tid>>3, 64B chunk (tid&7)*16 ----
    const int srow = tid >> 3;
    const int scol = (tid & 7) * 16;
    {
        int row = node0 + srow;
        int rc  = row < N ? row : N - 1;
        const float* p = node_repr + (long)rc * EMBED + scol;
        float4 r0 = *(const float4*)(p);
        float4 r1 = *(const float4*)(p + 4);
        float4 r2 = *(const float4*)(p + 8);
        float4 r3 = *(const float4*)(p + 12);
        float mrow = (row < N) ? mask[rc] : 0.f;

        float* dst = &sa[srow * LDSROW + scol];
        *(float4*)(dst)      = r0;
        *(float4*)(dst + 4)  = r1;
        *(float4*)(dst + 8)  = r2;
        *(float4*)(dst + 12) = r3;

        float pp = 0.f;
        pp = fmaf(r0.x,r0.x, fmaf(r0.y,r0.y, fmaf(r0.z,r0.z, fmaf(r0.w,r0.w, pp))));
        pp = fmaf(r1.x,r1.x, fmaf(r1.y,r1.y, fmaf(r1.z,r1.z, fmaf(r1.w,r1.w, pp))));
        pp = fmaf(r2.x,r2.x, fmaf(r2.y,r2.y, fmaf(r2.z,r2.z, fmaf(r2.w,r2.w, pp))));
        pp = fmaf(r3.x,r3.x, fmaf(r3.y,r3.y, fmaf(r3.z,r3.z, fmaf(r3.w,r3.w, pp))));
        pp += __shfl_xor(pp, 1); pp += __shfl_xor(pp, 2); pp += __shfl_xor(pp, 4);
        if ((tid & 7) == 0) { s_su[srow] = pp; s_ms[srow] = mrow; }
    }

    // ---- B: load + fp32 norm + bf16-pack once (held in 16 VGPRs) ----
    const float* bp = cent + (long)(cw + lm) * EMBED + quad * 8;
    float svp = 0.f;
    bf16x8 bb[4];
    #pragma unroll
    for (int ks = 0; ks < 4; ++ks) {
        float4 b0 = *(const float4*)(bp + ks * 32);
        float4 b1 = *(const float4*)(bp + ks * 32 + 4);
        svp = fmaf(b0.x,b0.x, fmaf(b0.y,b0.y, fmaf(b0.z,b0.z, fmaf(b0.w,b0.w, svp))));
        svp = fmaf(b1.x,b1.x, fmaf(b1.y,b1.y, fmaf(b1.z,b1.z, fmaf(b1.w,b1.w, svp))));
        bb[ks] = pack8(b0, b1);
    }
    svp += __shfl_xor(svp, 16); svp += __shfl_xor(svp, 32);
    const float sv1 = 1.f - svp;

    __syncthreads();                       // A tile + s_su/s_ms visible

    // ---- MFMA: 2 sub-tiles x 4 k-steps, B frags reused from registers ----
    f32x4 acc0 = {0.f,0.f,0.f,0.f}, acc1 = {0.f,0.f,0.f,0.f};
    #pragma unroll
    for (int ks = 0; ks < 4; ++ks) {
        const int base = quad * 8 + ks * 32;
        float4 a00 = *(const float4*)&sa[lm * LDSROW + base];
        float4 a01 = *(const float4*)&sa[lm * LDSROW + base + 4];
        float4 a10 = *(const float4*)&sa[(16 + lm) * LDSROW + base];
        float4 a11 = *(const float4*)&sa[(16 + lm) * LDSROW + base + 4];
        acc0 = __builtin_amdgcn_mfma_f32_16x16x32_bf16(pack8(a00, a01), bb[ks], acc0, 0, 0, 0);
        acc1 = __builtin_amdgcn_mfma_f32_16x16x32_bf16(pack8(a10, a11), bb[ks], acc1, 0, 0, 0);
    }

    // ---- epilogue: D layout col=lm (cent), row=quad*4+r (node) ----
    float gcol = 0.f;
    #pragma unroll
    for (int r = 0; r < 4; ++r) {
        const int m0 = quad * 4 + r;
        {   // sub-tile 0
            const int n = node0 + m0;
            const float su_m = s_su[m0];
            const float mk_m = s_ms[m0];
            float sq    = fmaxf(su_m + svp - 2.f * acc0[r], 0.f);
            float denom = fmaxf((1.f - su_m) * sv1, EPS);
            float tt    = fmaxf(2.f * sq * __builtin_amdgcn_rcpf(denom), EPS);
            float v     = __logf(1.f + tt + sqrtf(tt * (tt + 2.f))) * mk_m;
            if (n < N) { out[NUM_C + (long)n * NUM_C + cw + lm] = v; gcol += v; }
        }
        {   // sub-tile 1
            const int n = node0 + 16 + m0;
            const float su_m = s_su[16 + m0];
            const float mk_m = s_ms[16 + m0];
            float sq    = fmaxf(su_m + svp - 2.f * acc1[r], 0.f);
            float denom = fmaxf((1.f - su_m) * sv1, EPS);
            float tt    = fmaxf(2.f * sq * __builtin_amdgcn_rcpf(denom), EPS);
            float v     = __logf(1.f + tt + sqrtf(tt * (tt + 2.f))) * mk_m;
            if (n < N) { out[NUM_C + (long)n * NUM_C + cw + lm] = v; gcol += v; }
        }
    }

    // ---- accumulate partials into shadow banks (low-contention atomics) ----
    gcol += __shfl_xor(gcol, 16); gcol += __shfl_xor(gcol, 32);   // sum quads
    float* bank = acc + (blockIdx.x & (BANKS - 1)) * BSTRIDE;
    if (quad == 0) atomicAdd(&bank[cw + lm], gcol);
    if (wv == 0) {                          // after barrier: s_ms complete
        float ms = (lane < NPB) ? s_ms[lane] : 0.f;
        #pragma unroll
        for (int k = 32; k; k >>= 1) ms += __shfl_xor(ms, k, 64);
        if (lane == 0) atomicAdd(&bank[64], ms);
    }

    // ---- last-block finalize (single-pass reduce protocol) ----
    __syncthreads();                        // all waves' atomics issued+drained
    if (tid == 0) {
        __threadfence();                    // release: partials visible device-wide
        unsigned old = atomicAdd(cnt, 1u);
        s_last = (old == (unsigned)(nb - 1)) ? 1u : 0u;
    }
    __syncthreads();
    if (s_last) {
        __threadfence();                    // acquire
        if (tid < NUM_C) {
            float s = 0.f, m = 0.f;
            #pragma unroll
            for (int b = 0; b < BANKS; ++b) {
                s += acc[b * BSTRIDE + tid];
                m += acc[b * BSTRIDE + 64];
            }
            out[tid] = s / m;
        }
    }
}

extern "C" void kernel_launch(void* const* d_in, const int* in_sizes, int n_in,
                              void* d_out, int out_size, void* d_ws, size_t ws_size,
                              hipStream_t stream) {
    const float* node_repr = (const float*)d_in[0];
    const float* mask      = (const float*)d_in[1];
    const float* cent      = (const float*)d_in[2];
    float* out = (float*)d_out;

    const int N  = in_sizes[0] / EMBED;
    const int nb = (N + NPB - 1) / NPB;

    float*    acc = (float*)d_ws;                    // BANKS*BSTRIDE floats
    unsigned* cnt = (unsigned*)(acc + BANKS * BSTRIDE);

    // zero banks + counter (ws is poisoned 0xAA before every launch)
    hipMemsetAsync(d_ws, 0, (BANKS * BSTRIDE + 1) * sizeof(float), stream);
    cd_main<<<nb, 256, 0, stream>>>(node_repr, mask, cent, out, acc, cnt, N, nb);
}

// Round 10
// 78.172 us; speedup vs baseline: 1.1631x; 1.1631x over previous
//
#include <hip/hip_runtime.h>
#include <hip/hip_bf16.h>
#include <math.h>

#define EMBED  128
#define NUM_C  64
#define EPS    1e-5f
#define NPB    32            // nodes per block (one tile per block)
#define LDSROW 132           // floats; padded rows, bank-balanced b128 pattern
#define BANKS  16            // shadow accumulator banks (no atomic line contention)
#define BSTRIDE 80           // floats per bank: 64 col-sums + 1 mask + pad

typedef __attribute__((ext_vector_type(8))) short bf16x8;   // MFMA A/B frag
typedef __attribute__((ext_vector_type(4))) float f32x4;    // MFMA C/D frag

__device__ __forceinline__ bf16x8 pack8(float4 x, float4 y) {
    __hip_bfloat162 p0 = __float22bfloat162_rn(float2{x.x, x.y});
    __hip_bfloat162 p1 = __float22bfloat162_rn(float2{x.z, x.w});
    __hip_bfloat162 p2 = __float22bfloat162_rn(float2{y.x, y.y});
    __hip_bfloat162 p3 = __float22bfloat162_rn(float2{y.z, y.w});
    union { __hip_bfloat162 h[4]; bf16x8 v; } u;
    u.h[0] = p0; u.h[1] = p1; u.h[2] = p2; u.h[3] = p3;
    return u.v;
}

// Single compute kernel (R8 body) + last-block finalize WITHOUT __threadfence.
// Protocol correctness: bank atomicAdds are device-scope RMWs at the coherence
// point; the compiler's vmcnt(0) drain before s_barrier (m97 asm) guarantees
// every wave's atomics are acked before tid0 bumps the counter. Last block
// reads banks with AGENT-scope atomic loads (bypass stale local caches).
// R7 post-mortem: cooperative grid.sync ~ +60us. R9 post-mortem: per-block
// __threadfence (buffer_wbl2 storm) ~ +20us. Neither is needed.
__global__ __launch_bounds__(256) void cd_main(
    const float* __restrict__ node_repr,   // [N,128]
    const float* __restrict__ mask,        // [N,1]
    const float* __restrict__ cent,        // [64,128]
    float* __restrict__ out,               // [64 + N*64]
    float* __restrict__ acc,               // [BANKS*BSTRIDE] zeroed banks
    unsigned* __restrict__ cnt,            // zeroed block counter
    int N, int nb)
{
    __shared__ float sa[NPB * LDSROW];     // 16896 B A tile (padded rows)
    __shared__ float s_su[NPB];            // per-row ||u||^2
    __shared__ float s_ms[NPB];            // per-row mask (0 for OOB rows)
    __shared__ unsigned s_last;

    const int tid  = threadIdx.x;
    const int lane = tid & 63;
    const int wv   = tid >> 6;
    const int quad = lane >> 4;            // 0..3 (k-slice)
    const int lm   = lane & 15;            // A row in tile / B col / D col
    const int cw   = wv * 16;              // wave's centroid group base
    const int node0 = blockIdx.x * NPB;

    // ---- A staging: thread owns row tid>>3, 64B chunk (tid&7)*16 ----
    const int srow = tid >> 3;
    const int scol = (tid & 7) * 16;
    {
        int row = node0 + srow;
        int rc  = row < N ? row : N - 1;
        const float* p = node_repr + (long)rc * EMBED + scol;
        float4 r0 = *(const float4*)(p);
        float4 r1 = *(const float4*)(p + 4);
        float4 r2 = *(const float4*)(p + 8);
        float4 r3 = *(const float4*)(p + 12);
        float mrow = (row < N) ? mask[rc] : 0.f;

        float* dst = &sa[srow * LDSROW + scol];
        *(float4*)(dst)      = r0;
        *(float4*)(dst + 4)  = r1;
        *(float4*)(dst + 8)  = r2;
        *(float4*)(dst + 12) = r3;

        float pp = 0.f;
        pp = fmaf(r0.x,r0.x, fmaf(r0.y,r0.y, fmaf(r0.z,r0.z, fmaf(r0.w,r0.w, pp))));
        pp = fmaf(r1.x,r1.x, fmaf(r1.y,r1.y, fmaf(r1.z,r1.z, fmaf(r1.w,r1.w, pp))));
        pp = fmaf(r2.x,r2.x, fmaf(r2.y,r2.y, fmaf(r2.z,r2.z, fmaf(r2.w,r2.w, pp))));
        pp = fmaf(r3.x,r3.x, fmaf(r3.y,r3.y, fmaf(r3.z,r3.z, fmaf(r3.w,r3.w, pp))));
        pp += __shfl_xor(pp, 1); pp += __shfl_xor(pp, 2); pp += __shfl_xor(pp, 4);
        if ((tid & 7) == 0) { s_su[srow] = pp; s_ms[srow] = mrow; }
    }

    // ---- B: load + fp32 norm + bf16-pack once (held in 16 VGPRs) ----
    const float* bp = cent + (long)(cw + lm) * EMBED + quad * 8;
    float svp = 0.f;
    bf16x8 bb[4];
    #pragma unroll
    for (int ks = 0; ks < 4; ++ks) {
        float4 b0 = *(const float4*)(bp + ks * 32);
        float4 b1 = *(const float4*)(bp + ks * 32 + 4);
        svp = fmaf(b0.x,b0.x, fmaf(b0.y,b0.y, fmaf(b0.z,b0.z, fmaf(b0.w,b0.w, svp))));
        svp = fmaf(b1.x,b1.x, fmaf(b1.y,b1.y, fmaf(b1.z,b1.z, fmaf(b1.w,b1.w, svp))));
        bb[ks] = pack8(b0, b1);
    }
    svp += __shfl_xor(svp, 16); svp += __shfl_xor(svp, 32);
    const float sv1 = 1.f - svp;

    __syncthreads();                       // A tile + s_su/s_ms visible

    // ---- MFMA: 2 sub-tiles x 4 k-steps, B frags reused from registers ----
    f32x4 acc0 = {0.f,0.f,0.f,0.f}, acc1 = {0.f,0.f,0.f,0.f};
    #pragma unroll
    for (int ks = 0; ks < 4; ++ks) {
        const int base = quad * 8 + ks * 32;
        float4 a00 = *(const float4*)&sa[lm * LDSROW + base];
        float4 a01 = *(const float4*)&sa[lm * LDSROW + base + 4];
        float4 a10 = *(const float4*)&sa[(16 + lm) * LDSROW + base];
        float4 a11 = *(const float4*)&sa[(16 + lm) * LDSROW + base + 4];
        acc0 = __builtin_amdgcn_mfma_f32_16x16x32_bf16(pack8(a00, a01), bb[ks], acc0, 0, 0, 0);
        acc1 = __builtin_amdgcn_mfma_f32_16x16x32_bf16(pack8(a10, a11), bb[ks], acc1, 0, 0, 0);
    }

    // ---- epilogue: D layout col=lm (cent), row=quad*4+r (node) ----
    float gcol = 0.f;
    #pragma unroll
    for (int r = 0; r < 4; ++r) {
        const int m0 = quad * 4 + r;
        {   // sub-tile 0
            const int n = node0 + m0;
            const float su_m = s_su[m0];
            const float mk_m = s_ms[m0];
            float sq    = fmaxf(su_m + svp - 2.f * acc0[r], 0.f);
            float denom = fmaxf((1.f - su_m) * sv1, EPS);
            float tt    = fmaxf(2.f * sq * __builtin_amdgcn_rcpf(denom), EPS);
            float v     = __logf(1.f + tt + sqrtf(tt * (tt + 2.f))) * mk_m;
            if (n < N) { out[NUM_C + (long)n * NUM_C + cw + lm] = v; gcol += v; }
        }
        {   // sub-tile 1
            const int n = node0 + 16 + m0;
            const float su_m = s_su[16 + m0];
            const float mk_m = s_ms[16 + m0];
            float sq    = fmaxf(su_m + svp - 2.f * acc1[r], 0.f);
            float denom = fmaxf((1.f - su_m) * sv1, EPS);
            float tt    = fmaxf(2.f * sq * __builtin_amdgcn_rcpf(denom), EPS);
            float v     = __logf(1.f + tt + sqrtf(tt * (tt + 2.f))) * mk_m;
            if (n < N) { out[NUM_C + (long)n * NUM_C + cw + lm] = v; gcol += v; }
        }
    }

    // ---- accumulate partials into shadow banks (fire-and-forget atomics) ----
    gcol += __shfl_xor(gcol, 16); gcol += __shfl_xor(gcol, 32);   // sum quads
    float* bank = acc + (blockIdx.x & (BANKS - 1)) * BSTRIDE;
    if (quad == 0) atomicAdd(&bank[cw + lm], gcol);
    if (wv == 0) {                          // after barrier: s_ms complete
        float ms = (lane < NPB) ? s_ms[lane] : 0.f;
        #pragma unroll
        for (int k = 32; k; k >>= 1) ms += __shfl_xor(ms, k, 64);
        if (lane == 0) atomicAdd(&bank[64], ms);
    }

    // ---- last-block finalize: NO __threadfence (see header comment) ----
    __syncthreads();                        // drains every wave's vmcnt -> atomics acked
    if (tid == 0) {
        unsigned old = atomicAdd(cnt, 1u);
        s_last = (old == (unsigned)(nb - 1)) ? 1u : 0u;
    }
    __syncthreads();
    if (s_last && tid < NUM_C) {
        float s = 0.f, m = 0.f;
        #pragma unroll
        for (int b = 0; b < BANKS; ++b) {
            s += __hip_atomic_load(&acc[b * BSTRIDE + tid], __ATOMIC_RELAXED,
                                   __HIP_MEMORY_SCOPE_AGENT);
            m += __hip_atomic_load(&acc[b * BSTRIDE + 64], __ATOMIC_RELAXED,
                                   __HIP_MEMORY_SCOPE_AGENT);
        }
        out[tid] = s / m;
    }
}

extern "C" void kernel_launch(void* const* d_in, const int* in_sizes, int n_in,
                              void* d_out, int out_size, void* d_ws, size_t ws_size,
                              hipStream_t stream) {
    const float* node_repr = (const float*)d_in[0];
    const float* mask      = (const float*)d_in[1];
    const float* cent      = (const float*)d_in[2];
    float* out = (float*)d_out;

    const int N  = in_sizes[0] / EMBED;
    const int nb = (N + NPB - 1) / NPB;

    float*    acc = (float*)d_ws;                    // BANKS*BSTRIDE floats
    unsigned* cnt = (unsigned*)(acc + BANKS * BSTRIDE);

    // zero banks + counter (ws is poisoned 0xAA before every launch)
    hipMemsetAsync(d_ws, 0, (BANKS * BSTRIDE + 1) * sizeof(float), stream);
    cd_main<<<nb, 256, 0, stream>>>(node_repr, mask, cent, out, acc, cnt, N, nb);
}

// Round 11
// 72.224 us; speedup vs baseline: 1.2589x; 1.0824x over previous
//
#include <hip/hip_runtime.h>
#include <hip/hip_bf16.h>
#include <math.h>

#define EMBED  128
#define NUM_C  64
#define EPS    1e-5f
#define NPB    32            // nodes per block (one tile per block)
#define LDSROW 132           // floats; padded rows, bank-balanced b128 pattern

typedef __attribute__((ext_vector_type(8))) short bf16x8;   // MFMA A/B frag
typedef __attribute__((ext_vector_type(4))) float f32x4;    // MFMA C/D frag

__device__ __forceinline__ bf16x8 pack8(float4 x, float4 y) {
    __hip_bfloat162 p0 = __float22bfloat162_rn(float2{x.x, x.y});
    __hip_bfloat162 p1 = __float22bfloat162_rn(float2{x.z, x.w});
    __hip_bfloat162 p2 = __float22bfloat162_rn(float2{y.x, y.y});
    __hip_bfloat162 p3 = __float22bfloat162_rn(float2{y.z, y.w});
    union { __hip_bfloat162 h[4]; bf16x8 v; } u;
    u.h[0] = p0; u.h[1] = p1; u.h[2] = p2; u.h[3] = p3;
    return u.v;
}

// R8 configuration == empirical optimum of this session (72.5 us).
// One block = one 32-node x 64-centroid tile: A staged to LDS once (coalesced,
// no per-wave duplication), B packed to bf16 frags once per wave, ONE barrier,
// no atomics in the main path; partials go to a transposed [64][nb] workspace
// reduced by a 64-block kernel.
// Post-mortems encoded here:
//   R7: cooperative grid.sync ~= +60us on this harness -- never.
//   R9: per-block __threadfence (buffer_wbl2 storm) ~= +20us.
//   R10: fence-free last-block atomic protocol still +6us vs this shape
//        (625x extra exit barriers/counter RMW > one 3us reduce kernel).
__global__ __launch_bounds__(256) void cd_main(
    const float* __restrict__ node_repr,   // [N,128]
    const float* __restrict__ mask,        // [N,1]
    const float* __restrict__ cent,        // [64,128]
    float* __restrict__ out,               // [64 + N*64]
    float* __restrict__ wcol,              // [64][nb] transposed column partials
    float* __restrict__ wmsk,              // [nb] mask partials
    int N, int nb, int atomicMode)
{
    __shared__ float sa[NPB * LDSROW];     // 16896 B A tile (padded rows)
    __shared__ float s_su[NPB];            // per-row ||u||^2
    __shared__ float s_ms[NPB];            // per-row mask (0 for OOB rows)

    const int tid  = threadIdx.x;
    const int lane = tid & 63;
    const int wv   = tid >> 6;
    const int quad = lane >> 4;            // 0..3 (k-slice)
    const int lm   = lane & 15;            // A row in tile / B col / D col
    const int cw   = wv * 16;              // wave's centroid group base
    const int node0 = blockIdx.x * NPB;

    // ---- A staging: thread owns row tid>>3, 64B chunk (tid&7)*16 ----
    const int srow = tid >> 3;
    const int scol = (tid & 7) * 16;
    {
        int row = node0 + srow;
        int rc  = row < N ? row : N - 1;
        const float* p = node_repr + (long)rc * EMBED + scol;
        float4 r0 = *(const float4*)(p);
        float4 r1 = *(const float4*)(p + 4);
        float4 r2 = *(const float4*)(p + 8);
        float4 r3 = *(const float4*)(p + 12);
        float mrow = (row < N) ? mask[rc] : 0.f;

        float* dst = &sa[srow * LDSROW + scol];
        *(float4*)(dst)      = r0;
        *(float4*)(dst + 4)  = r1;
        *(float4*)(dst + 8)  = r2;
        *(float4*)(dst + 12) = r3;

        float pp = 0.f;
        pp = fmaf(r0.x,r0.x, fmaf(r0.y,r0.y, fmaf(r0.z,r0.z, fmaf(r0.w,r0.w, pp))));
        pp = fmaf(r1.x,r1.x, fmaf(r1.y,r1.y, fmaf(r1.z,r1.z, fmaf(r1.w,r1.w, pp))));
        pp = fmaf(r2.x,r2.x, fmaf(r2.y,r2.y, fmaf(r2.z,r2.z, fmaf(r2.w,r2.w, pp))));
        pp = fmaf(r3.x,r3.x, fmaf(r3.y,r3.y, fmaf(r3.z,r3.z, fmaf(r3.w,r3.w, pp))));
        pp += __shfl_xor(pp, 1); pp += __shfl_xor(pp, 2); pp += __shfl_xor(pp, 4);
        if ((tid & 7) == 0) { s_su[srow] = pp; s_ms[srow] = mrow; }
    }

    // ---- B: load + fp32 norm + bf16-pack once (held in 16 VGPRs) ----
    const float* bp = cent + (long)(cw + lm) * EMBED + quad * 8;
    float svp = 0.f;
    bf16x8 bb[4];
    #pragma unroll
    for (int ks = 0; ks < 4; ++ks) {
        float4 b0 = *(const float4*)(bp + ks * 32);
        float4 b1 = *(const float4*)(bp + ks * 32 + 4);
        svp = fmaf(b0.x,b0.x, fmaf(b0.y,b0.y, fmaf(b0.z,b0.z, fmaf(b0.w,b0.w, svp))));
        svp = fmaf(b1.x,b1.x, fmaf(b1.y,b1.y, fmaf(b1.z,b1.z, fmaf(b1.w,b1.w, svp))));
        bb[ks] = pack8(b0, b1);
    }
    svp += __shfl_xor(svp, 16); svp += __shfl_xor(svp, 32);
    const float sv1 = 1.f - svp;

    __syncthreads();                       // A tile + s_su/s_ms visible

    // ---- MFMA: 2 sub-tiles x 4 k-steps, B frags reused from registers ----
    f32x4 acc0 = {0.f,0.f,0.f,0.f}, acc1 = {0.f,0.f,0.f,0.f};
    #pragma unroll
    for (int ks = 0; ks < 4; ++ks) {
        const int base = quad * 8 + ks * 32;
        float4 a00 = *(const float4*)&sa[lm * LDSROW + base];
        float4 a01 = *(const float4*)&sa[lm * LDSROW + base + 4];
        float4 a10 = *(const float4*)&sa[(16 + lm) * LDSROW + base];
        float4 a11 = *(const float4*)&sa[(16 + lm) * LDSROW + base + 4];
        acc0 = __builtin_amdgcn_mfma_f32_16x16x32_bf16(pack8(a00, a01), bb[ks], acc0, 0, 0, 0);
        acc1 = __builtin_amdgcn_mfma_f32_16x16x32_bf16(pack8(a10, a11), bb[ks], acc1, 0, 0, 0);
    }

    // ---- epilogue: D layout col=lm (cent), row=quad*4+r (node) ----
    float gcol = 0.f;
    #pragma unroll
    for (int r = 0; r < 4; ++r) {
        const int m0 = quad * 4 + r;
        {   // sub-tile 0
            const int n = node0 + m0;
            const float su_m = s_su[m0];
            const float mk_m = s_ms[m0];
            float sq    = fmaxf(su_m + svp - 2.f * acc0[r], 0.f);
            float denom = fmaxf((1.f - su_m) * sv1, EPS);
            float tt    = fmaxf(2.f * sq * __builtin_amdgcn_rcpf(denom), EPS);
            float v     = __logf(1.f + tt + sqrtf(tt * (tt + 2.f))) * mk_m;
            if (n < N) { out[NUM_C + (long)n * NUM_C + cw + lm] = v; gcol += v; }
        }
        {   // sub-tile 1
            const int n = node0 + 16 + m0;
            const float su_m = s_su[16 + m0];
            const float mk_m = s_ms[16 + m0];
            float sq    = fmaxf(su_m + svp - 2.f * acc1[r], 0.f);
            float denom = fmaxf((1.f - su_m) * sv1, EPS);
            float tt    = fmaxf(2.f * sq * __builtin_amdgcn_rcpf(denom), EPS);
            float v     = __logf(1.f + tt + sqrtf(tt * (tt + 2.f))) * mk_m;
            if (n < N) { out[NUM_C + (long)n * NUM_C + cw + lm] = v; gcol += v; }
        }
    }

    // ---- partials: columns (transposed for coalesced reduce) + block mask ----
    gcol += __shfl_xor(gcol, 16); gcol += __shfl_xor(gcol, 32);   // sum quads
    if (quad == 0) {
        if (atomicMode) atomicAdd(&wcol[cw + lm], gcol);
        else            wcol[(long)(cw + lm) * nb + blockIdx.x] = gcol;
    }
    if (wv == 0) {                          // after barrier: s_ms complete
        float ms = (lane < NPB) ? s_ms[lane] : 0.f;
        #pragma unroll
        for (int k = 32; k; k >>= 1) ms += __shfl_xor(ms, k, 64);
        if (lane == 0) {
            if (atomicMode) atomicAdd(&wmsk[0], ms);
            else            wmsk[blockIdx.x] = ms;
        }
    }
}

// Reduce: 64 blocks; block c sums its contiguous column + (redundantly) mask.
__global__ __launch_bounds__(256) void cd_fin1(
    const float* __restrict__ wcol, const float* __restrict__ wmsk,
    float* __restrict__ out, int nb)
{
    __shared__ float rs[4], rm[4];
    const int c   = blockIdx.x;
    const int tid = threadIdx.x;

    float s = 0.f, m = 0.f;
    for (int b = tid; b < nb; b += 256) {
        s += wcol[(long)c * nb + b];        // coalesced: contiguous column
        m += wmsk[b];
    }
    #pragma unroll
    for (int k = 32; k; k >>= 1) { s += __shfl_xor(s, k, 64); m += __shfl_xor(m, k, 64); }
    if ((tid & 63) == 0) { rs[tid >> 6] = s; rm[tid >> 6] = m; }
    __syncthreads();
    if (tid == 0)
        out[c] = (rs[0] + rs[1] + rs[2] + rs[3]) / (rm[0] + rm[1] + rm[2] + rm[3]);
}

// atomic-mode fallback helpers
__global__ void cd_zero(float* acc) { if (threadIdx.x < NUM_C + 1) acc[threadIdx.x] = 0.f; }
__global__ void cd_fin_atomic(const float* __restrict__ acc, float* __restrict__ out) {
    int c = threadIdx.x;
    if (c < NUM_C) out[c] = acc[c] / acc[NUM_C];
}

extern "C" void kernel_launch(void* const* d_in, const int* in_sizes, int n_in,
                              void* d_out, int out_size, void* d_ws, size_t ws_size,
                              hipStream_t stream) {
    const float* node_repr = (const float*)d_in[0];
    const float* mask      = (const float*)d_in[1];
    const float* cent      = (const float*)d_in[2];
    float* out = (float*)d_out;

    const int N  = in_sizes[0] / EMBED;
    const int nb = (N + NPB - 1) / NPB;
    const size_t needed = ((size_t)NUM_C * nb + nb) * sizeof(float);

    if (ws_size >= needed) {
        float* wcol = (float*)d_ws;                  // [64][nb] transposed
        float* wmsk = wcol + (size_t)NUM_C * nb;     // [nb]
        cd_main<<<nb, 256, 0, stream>>>(node_repr, mask, cent, out, wcol, wmsk, N, nb, 0);
        cd_fin1<<<NUM_C, 256, 0, stream>>>(wcol, wmsk, out, nb);
    } else {
        float* acc = (float*)d_ws;   // 65 floats
        cd_zero<<<1, 128, 0, stream>>>(acc);
        cd_main<<<nb, 256, 0, stream>>>(node_repr, mask, cent, out, acc, acc + NUM_C, N, nb, 1);
        cd_fin_atomic<<<1, 64, 0, stream>>>(acc, out);
    }
}